// Round 1
// baseline (2562.294 us; speedup 1.0000x reference)
//
#include <hip/hip_runtime.h>
#include <stdint.h>

#define NF 65536
#define DIM 512
#define NATTR 256
#define NSTEP 16

typedef __attribute__((ext_vector_type(8))) short s16x8;
typedef __attribute__((ext_vector_type(4))) float f32x4;

__device__ __forceinline__ unsigned short f2bf(float f) {
  union { float f; unsigned u; } v; v.f = f;
  return (unsigned short)((v.u + 0x7fffu + ((v.u >> 16) & 1u)) >> 16);
}
__device__ __forceinline__ float bf2f(unsigned short b) {
  union { unsigned u; float f; } v; v.u = ((unsigned)b) << 16;
  return v.f;
}

// ---------------- prep: column sums of fe (for h0 = mean(fe)@W_ctx + b_ctx) ----------------
__global__ void k_colsum(const float* __restrict__ fe, float* __restrict__ colsum) {
  int c = threadIdx.x;                 // 256 threads, 2 cols each
  int r0 = blockIdx.x * 256;           // 256 blocks x 256 rows
  float s0 = 0.f, s1 = 0.f;
  for (int r = r0; r < r0 + 256; ++r) {
    s0 += fe[(size_t)r * DIM + c];
    s1 += fe[(size_t)r * DIM + c + 256];
  }
  atomicAdd(&colsum[c], s0);
  atomicAdd(&colsum[c + 256], s1);
}

// ---------------- prep: transpose Wk, Wv (512x512) ----------------
__global__ void k_transpose2(const float* __restrict__ wk, const float* __restrict__ wv,
                             float* __restrict__ wkt, float* __restrict__ wvt) {
  __shared__ float t[64][65];
  const float* src = blockIdx.z ? wv : wk;
  float* dst = blockIdx.z ? wvt : wkt;
  int c0 = blockIdx.x * 64, r0 = blockIdx.y * 64;
  for (int i = 0; i < 16; ++i) {
    int row = i * 4 + (threadIdx.x >> 6), col = threadIdx.x & 63;
    t[row][col] = src[(r0 + row) * 512 + c0 + col];
  }
  __syncthreads();
  for (int i = 0; i < 16; ++i) {
    int row = i * 4 + (threadIdx.x >> 6), col = threadIdx.x & 63;
    dst[(c0 + row) * 512 + r0 + col] = t[col][row];
  }
}

// ---------------- prep: generic C[M][N] = sum_k A[m][k]*B[n][k]  (K=512) ----------------
// A row stride lda with column offset aoff; B row stride ldb. Output fp32 or bf16.
template <bool BF16OUT>
__global__ void k_abt(const float* __restrict__ A, int lda, int aoff,
                      const float* __restrict__ B, int ldb,
                      void* __restrict__ C, int ldc, int mbase) {
  __shared__ float ta[64][65], tb[64][65];
  int m0 = blockIdx.y * 64, n0 = blockIdx.x * 64;
  int tid = threadIdx.x;
  float acc[4][4] = {};
  for (int k0 = 0; k0 < 512; k0 += 64) {
    __syncthreads();
    for (int i = 0; i < 16; ++i) {
      int e = i * 256 + tid;
      int row = e >> 6, col = e & 63;
      ta[row][col] = A[(m0 + row) * lda + aoff + k0 + col];
      tb[row][col] = B[(n0 + row) * ldb + k0 + col];
    }
    __syncthreads();
    int tr = (tid >> 4) * 4, tc = (tid & 15) * 4;
#pragma unroll 4
    for (int k = 0; k < 64; ++k) {
      float av[4], bv[4];
#pragma unroll
      for (int i = 0; i < 4; ++i) av[i] = ta[tr + i][k];
#pragma unroll
      for (int j = 0; j < 4; ++j) bv[j] = tb[tc + j][k];
#pragma unroll
      for (int i = 0; i < 4; ++i)
#pragma unroll
        for (int j = 0; j < 4; ++j) acc[i][j] += av[i] * bv[j];
    }
  }
  int tr = (tid >> 4) * 4, tc = (tid & 15) * 4;
  for (int i = 0; i < 4; ++i)
    for (int j = 0; j < 4; ++j) {
      int m = mbase + m0 + tr + i, n = n0 + tc + j;
      if (BF16OUT) ((unsigned short*)C)[(size_t)m * ldc + n] = f2bf(acc[i][j]);
      else ((float*)C)[(size_t)m * ldc + n] = acc[i][j];
    }
}

// ---------------- prep: bc[n] = b_ctx @ Wsel[:,n] + bsel[n]  (n in 0..1023, k|v) ----------------
__global__ void k_bc(const float* __restrict__ wk, const float* __restrict__ bk,
                     const float* __restrict__ wv, const float* __restrict__ bv,
                     const float* __restrict__ bctx, float* __restrict__ bc) {
  int n = blockIdx.x * 256 + threadIdx.x;
  const float* w = n < 512 ? wk : wv;
  const float* b = n < 512 ? bk : bv;
  int col = n & 511;
  float s = b[col];
  for (int t = 0; t < 512; ++t) s += bctx[t] * w[t * 512 + col];
  bc[n] = s;
}

// ---------------- prep: bias2[r] = b_ih[r] + W_ih[r,256:] @ bo ----------------
__global__ void k_bias2(const float* __restrict__ wih, const float* __restrict__ bih,
                        const float* __restrict__ bo, float* __restrict__ bias2) {
  int r = blockIdx.x * 4 + (threadIdx.x >> 6);
  int l = threadIdx.x & 63;
  float s = 0.f;
  for (int j = l; j < 512; j += 64) s += wih[r * 768 + 256 + j] * bo[j];
  for (int mk = 1; mk < 64; mk <<= 1) s += __shfl_xor(s, mk);
  if (l == 0) bias2[r] = s + bih[r];
}

// ---------------- prep: h0 + copy start token ----------------
__global__ void k_h0(const float* __restrict__ wctx, const float* __restrict__ bctx,
                     const float* __restrict__ colsum, const float* __restrict__ stok,
                     float* __restrict__ h, float* __restrict__ pa) {
  if (blockIdx.x == 8) {
    if (threadIdx.x < 256) pa[threadIdx.x] = stok[threadIdx.x];
    return;
  }
  __shared__ float red[4][64];
  int c = blockIdx.x * 64 + (threadIdx.x & 63);
  int chunk = threadIdx.x >> 6;
  float s = 0.f;
  for (int i = chunk * 128; i < chunk * 128 + 128; ++i) s += colsum[i] * wctx[i * 512 + c];
  red[chunk][threadIdx.x & 63] = s;
  __syncthreads();
  if (threadIdx.x < 64) {
    int cc = blockIdx.x * 64 + threadIdx.x;
    float v = red[0][threadIdx.x] + red[1][threadIdx.x] + red[2][threadIdx.x] + red[3][threadIdx.x];
    h[cc] = v * (1.0f / NF) + bctx[cc];
  }
}

// ---------------- prep: qs = (h @ Wq + bq) / 8 ----------------
__global__ void k_q0(const float* __restrict__ h, const float* __restrict__ wq,
                     const float* __restrict__ bq, float* __restrict__ qs) {
  __shared__ float red[4][64];
  int j = blockIdx.x * 64 + (threadIdx.x & 63);
  int chunk = threadIdx.x >> 6;
  float s = 0.f;
  for (int i = chunk * 128; i < chunk * 128 + 128; ++i) s += h[i] * wq[i * 512 + j];
  red[chunk][threadIdx.x & 63] = s;
  __syncthreads();
  if (threadIdx.x < 64) {
    int jj = blockIdx.x * 64 + threadIdx.x;
    float v = red[0][threadIdx.x] + red[1][threadIdx.x] + red[2][threadIdx.x] + red[3][threadIdx.x];
    qs[jj] = (v + bq[jj]) * 0.125f;
  }
}

// ---------------- big dual GEMM: C_kv[65536][1024](bf16) = fe @ Bt^T + bc ----------------
// Bt is [1024][512] bf16 (row n holds the 512 K-weights), MFMA 16x16x32 bf16,
// 128x128 tile, BK=64, reg-staged A (fp32->bf16 convert), XOR-swizzled LDS.
__global__ __launch_bounds__(256) void k_gemm(const float* __restrict__ fe,
                                              const unsigned short* __restrict__ bt,
                                              const float* __restrict__ bc,
                                              unsigned short* __restrict__ ckv) {
  __shared__ unsigned short lA[128 * 64];
  __shared__ unsigned short lB[128 * 64];
  int bx = blockIdx.x;
  int m0 = (bx >> 3) * 128, n0 = (bx & 7) * 128;
  int t = threadIdx.x, l = t & 63, w = t >> 6;
  int wr = (w >> 1) * 64, wc = (w & 1) * 64;
  int lm = l & 15, lkb = (l >> 4) * 16;  // frag byte slot within row
  int swz = (lm & 7) << 4;
  f32x4 acc[4][4] = {};
  for (int k0 = 0; k0 < 512; k0 += 64) {
    __syncthreads();
#pragma unroll
    for (int i = 0; i < 8; ++i) {  // stage A: 128x64 fp32 -> bf16
      int e = i * 1024 + t * 4;
      int row = e >> 6, col = e & 63;
      float4 v = *(const float4*)&fe[(size_t)(m0 + row) * 512 + k0 + col];
      unsigned long long pk;
      unsigned short* pu = (unsigned short*)&pk;
      pu[0] = f2bf(v.x); pu[1] = f2bf(v.y); pu[2] = f2bf(v.z); pu[3] = f2bf(v.w);
      *(unsigned long long*)((char*)lA + row * 128 + ((col * 2) ^ ((row & 7) << 4))) = pk;
    }
#pragma unroll
    for (int i = 0; i < 4; ++i) {  // stage B: 128x64 bf16
      int e = i * 2048 + t * 8;
      int row = e >> 6, col = e & 63;
      uint4 v = *(const uint4*)&bt[(size_t)(n0 + row) * 512 + k0 + col];
      *(uint4*)((char*)lB + row * 128 + ((col * 2) ^ ((row & 7) << 4))) = v;
    }
    __syncthreads();
#pragma unroll
    for (int ks = 0; ks < 2; ++ks) {
      s16x8 af[4], bf_[4];
      int kb = ks * 64 + lkb;
#pragma unroll
      for (int mi = 0; mi < 4; ++mi)
        af[mi] = *(const s16x8*)((const char*)lA + (wr + mi * 16 + lm) * 128 + (kb ^ swz));
#pragma unroll
      for (int ni = 0; ni < 4; ++ni)
        bf_[ni] = *(const s16x8*)((const char*)lB + (wc + ni * 16 + lm) * 128 + (kb ^ swz));
#pragma unroll
      for (int mi = 0; mi < 4; ++mi)
#pragma unroll
        for (int ni = 0; ni < 4; ++ni)
          acc[mi][ni] = __builtin_amdgcn_mfma_f32_16x16x32_bf16(af[mi], bf_[ni], acc[mi][ni], 0, 0, 0);
    }
  }
#pragma unroll
  for (int mi = 0; mi < 4; ++mi)
#pragma unroll
    for (int ni = 0; ni < 4; ++ni) {
      int n = n0 + wc + ni * 16 + lm;
      float bias = bc[n];
#pragma unroll
      for (int r = 0; r < 4; ++r) {
        int m = m0 + wr + mi * 16 + (l >> 4) * 4 + r;
        ckv[(size_t)m * 1024 + n] = f2bf(acc[mi][ni][r] + bias);
      }
    }
}

// ---------------- step: streaming attention pass with online softmax ----------------
// ckv rows: [k(512 bf16) | v(512 bf16)]. Lane l owns cols l*8..l*8+7 (head l>>3).
__global__ __launch_bounds__(256) void k_attn(const unsigned short* __restrict__ ckv,
                                              const float* __restrict__ qs,
                                              float* __restrict__ pm, float* __restrict__ pz,
                                              float* __restrict__ pctx) {
  int t = threadIdx.x, l = t & 63, w = t >> 6;
  int h = l >> 3;
  float qr[8];
  {
    float4 q0 = *(const float4*)&qs[l * 8];
    float4 q1 = *(const float4*)&qs[l * 8 + 4];
    qr[0] = q0.x; qr[1] = q0.y; qr[2] = q0.z; qr[3] = q0.w;
    qr[4] = q1.x; qr[5] = q1.y; qr[6] = q1.z; qr[7] = q1.w;
  }
  float m = -1e30f, Z = 0.f, acc[8] = {};
  int r0 = blockIdx.x * 64 + w * 16;
#pragma unroll 2
  for (int r = r0; r < r0 + 16; ++r) {
    const uint4* row = (const uint4*)(ckv + (size_t)r * 1024);
    uint4 kv = row[l];
    uint4 vv = row[64 + l];
    float dot = 0.f;
    unsigned ku[4] = {kv.x, kv.y, kv.z, kv.w};
#pragma unroll
    for (int j = 0; j < 4; ++j) {
      dot += bf2f((unsigned short)(ku[j] & 0xffffu)) * qr[2 * j];
      dot += bf2f((unsigned short)(ku[j] >> 16)) * qr[2 * j + 1];
    }
    dot += __shfl_xor(dot, 1);
    dot += __shfl_xor(dot, 2);
    dot += __shfl_xor(dot, 4);
    unsigned vu[4] = {vv.x, vv.y, vv.z, vv.w};
    float vf[8];
#pragma unroll
    for (int j = 0; j < 4; ++j) {
      vf[2 * j] = bf2f((unsigned short)(vu[j] & 0xffffu));
      vf[2 * j + 1] = bf2f((unsigned short)(vu[j] >> 16));
    }
    if (dot <= m) {
      float wg = __expf(dot - m);
      Z += wg;
#pragma unroll
      for (int j = 0; j < 8; ++j) acc[j] += wg * vf[j];
    } else {
      float f = __expf(m - dot);
      Z = Z * f + 1.f;
#pragma unroll
      for (int j = 0; j < 8; ++j) acc[j] = acc[j] * f + vf[j];
      m = dot;
    }
  }
  __shared__ float sm[4][8], sz[4][8], sc[4][8][64];
  if ((l & 7) == 0) { sm[w][h] = m; sz[w][h] = Z; }
#pragma unroll
  for (int j = 0; j < 8; ++j) sc[w][h][(l & 7) * 8 + j] = acc[j];
  __syncthreads();
  for (int i = t; i < 512; i += 256) {
    int hh = i >> 6, d = i & 63;
    float M = fmaxf(fmaxf(sm[0][hh], sm[1][hh]), fmaxf(sm[2][hh], sm[3][hh]));
    float c = 0.f;
    for (int ww = 0; ww < 4; ++ww) c += sc[ww][hh][d] * __expf(sm[ww][hh] - M);
    pctx[((size_t)blockIdx.x * 8 + hh) * 64 + d] = c;
    if (d == 0) {
      float zz = 0.f;
      for (int ww = 0; ww < 4; ++ww) zz += sz[ww][hh] * __expf(sm[ww][hh] - M);
      pm[blockIdx.x * 8 + hh] = M;
      pz[blockIdx.x * 8 + hh] = zz;
    }
  }
}

// ---------------- step: combine block partials -> normalized ctx[512] ----------------
__global__ void k_combine(const float* __restrict__ pm, const float* __restrict__ pz,
                          const float* __restrict__ pctx, float* __restrict__ ctx) {
  int h = blockIdx.x, t = threadIdx.x;
  __shared__ float smax[256];
  float lm = -1e30f;
  for (int b = t; b < 1024; b += 256) lm = fmaxf(lm, pm[b * 8 + h]);
  smax[t] = lm;
  __syncthreads();
  for (int s = 128; s > 0; s >>= 1) {
    if (t < s) smax[t] = fmaxf(smax[t], smax[t + s]);
    __syncthreads();
  }
  float M = smax[0];
  int d = t & 63, g = t >> 6;
  float ca = 0.f, za = 0.f;
  for (int b = g; b < 1024; b += 4) {
    float f = __expf(pm[b * 8 + h] - M);
    ca += pctx[((size_t)b * 8 + h) * 64 + d] * f;
    if (d == 0) za += pz[b * 8 + h] * f;
  }
  __shared__ float cs[4][64], zs[4];
  cs[g][d] = ca;
  if (d == 0) zs[g] = za;
  __syncthreads();
  if (t < 64) {
    float c = cs[0][t] + cs[1][t] + cs[2][t] + cs[3][t];
    float Zt = zs[0] + zs[1] + zs[2] + zs[3];
    ctx[h * 64 + t] = c / Zt;
  }
}

// ---------------- step: ih_pre = G@ctx + W_ih[:, :256]@pa + bias2 ; hh = W_hh@h ----------------
__global__ void k_matvec(const float* __restrict__ G, const float* __restrict__ wih,
                         const float* __restrict__ whh, const float* __restrict__ bias2,
                         const float* __restrict__ ctx, const float* __restrict__ pa,
                         const float* __restrict__ h, float* __restrict__ ihp,
                         float* __restrict__ hh) {
  int r = blockIdx.x * 4 + (threadIdx.x >> 6);
  int l = threadIdx.x & 63;
  float s = 0.f;
  if (r < 1536) {
    for (int i = l; i < 512; i += 64) s += G[r * 512 + i] * ctx[i];
    for (int i = l; i < 256; i += 64) s += wih[r * 768 + i] * pa[i];
  } else {
    int r2 = r - 1536;
    for (int i = l; i < 512; i += 64) s += whh[r2 * 512 + i] * h[i];
  }
  for (int mk = 1; mk < 64; mk <<= 1) s += __shfl_xor(s, mk);
  if (l == 0) {
    if (r < 1536) ihp[r] = s + bias2[r];
    else hh[r - 1536] = s;
  }
}

// ---------------- step: GRU gates + heads + next q ----------------
__global__ void k_finish(const float* __restrict__ ihp, const float* __restrict__ hhv,
                         const float* __restrict__ bhn, const float* __restrict__ hold,
                         const float* __restrict__ wq, const float* __restrict__ bq,
                         const float* __restrict__ wattr, const float* __restrict__ battr,
                         const float* __restrict__ wconf, const float* __restrict__ bconf,
                         float* __restrict__ hnew_g, float* __restrict__ panew,
                         float* __restrict__ qs, float* __restrict__ out_a,
                         float* __restrict__ out_c) {
  __shared__ float hn[512];
  __shared__ float red[4][64];
  int t = threadIdx.x;
  for (int c = t; c < 512; c += 256) {
    float ir = ihp[c], iz = ihp[512 + c], inn = ihp[1024 + c];
    float hr = hhv[c], hz = hhv[512 + c], hnn = hhv[1024 + c];
    float r = 1.f / (1.f + __expf(-(ir + hr)));
    float z = 1.f / (1.f + __expf(-(iz + hz)));
    float n = tanhf(inn + r * (hnn + bhn[c]));
    hn[c] = (1.f - z) * n + z * hold[c];
  }
  __syncthreads();
  int b = blockIdx.x;
  if (b < 8) {  // next-step q (64 cols each)
    int j = b * 64 + (t & 63), chunk = t >> 6;
    float s = 0.f;
    for (int i = chunk * 128; i < chunk * 128 + 128; ++i) s += hn[i] * wq[i * 512 + j];
    red[chunk][t & 63] = s;
    __syncthreads();
    if (t < 64) {
      int jj = b * 64 + t;
      qs[jj] = (red[0][t] + red[1][t] + red[2][t] + red[3][t] + bq[jj]) * 0.125f;
    }
  } else if (b < 72) {  // attractor head, 4 rows per block
    int r = (b - 8) * 4 + (t >> 6), l = t & 63;
    float s = 0.f;
    for (int i = l; i < 512; i += 64) s += wattr[r * 512 + i] * hn[i];
    for (int mk = 1; mk < 64; mk <<= 1) s += __shfl_xor(s, mk);
    if (l == 0) {
      float a = s + battr[r];
      out_a[r] = a;
      panew[r] = a;
    }
  } else {  // confidence + publish h_new
    if (t < 64) {
      float s = 0.f;
      for (int i = t; i < 512; i += 64) s += wconf[i] * hn[i];
      for (int mk = 1; mk < 64; mk <<= 1) s += __shfl_xor(s, mk);
      if (t == 0) out_c[0] = 1.f / (1.f + __expf(-(s + bconf[0])));
    }
    for (int c = t; c < 512; c += 256) hnew_g[c] = hn[c];
  }
}

extern "C" void kernel_launch(void* const* d_in, const int* in_sizes, int n_in,
                              void* d_out, int out_size, void* d_ws, size_t ws_size,
                              hipStream_t stream) {
  (void)in_sizes; (void)n_in; (void)out_size; (void)ws_size;
  const float* fe    = (const float*)d_in[0];
  const float* wctx  = (const float*)d_in[1];
  const float* bctx  = (const float*)d_in[2];
  const float* wq    = (const float*)d_in[3];
  const float* bq    = (const float*)d_in[4];
  const float* wk    = (const float*)d_in[5];
  const float* bk    = (const float*)d_in[6];
  const float* wv    = (const float*)d_in[7];
  const float* bv    = (const float*)d_in[8];
  const float* wo    = (const float*)d_in[9];
  const float* bo    = (const float*)d_in[10];
  const float* wih   = (const float*)d_in[11];
  const float* whh   = (const float*)d_in[12];
  const float* bih   = (const float*)d_in[13];
  const float* bhn   = (const float*)d_in[14];
  const float* stok  = (const float*)d_in[15];
  const float* wattr = (const float*)d_in[16];
  const float* battr = (const float*)d_in[17];
  const float* wconf = (const float*)d_in[18];
  const float* bconf = (const float*)d_in[19];
  float* out = (float*)d_out;

  char* ws = (char*)d_ws;
  unsigned short* ckv   = (unsigned short*)(ws + 0);            // 134217728 B
  unsigned short* btmat = (unsigned short*)(ws + 134217728);    // 1048576 B
  float* wkt    = (float*)(ws + 135266304);                     // 1048576
  float* wvt    = (float*)(ws + 136314880);                     // 1048576
  float* gmat   = (float*)(ws + 137363456);                     // 3145728
  float* bcv    = (float*)(ws + 140509184);                     // 4096
  float* bias2  = (float*)(ws + 140513280);                     // 6144
  float* colsum = (float*)(ws + 140519424);                     // 2048
  float* hbuf   = (float*)(ws + 140521472);                     // 2*512*4
  float* pabuf  = (float*)(ws + 140525568);                     // 2*256*4
  float* qsbuf  = (float*)(ws + 140527616);                     // 512*4
  float* ctxbuf = (float*)(ws + 140529664);                     // 512*4
  float* ihpb   = (float*)(ws + 140531712);                     // 1536*4
  float* hhb    = (float*)(ws + 140537856);                     // 1536*4
  float* pmb    = (float*)(ws + 140544000);                     // 8192*4
  float* pzb    = (float*)(ws + 140576768);                     // 8192*4
  float* pctxb  = (float*)(ws + 140609536);                     // 524288*4

  hipMemsetAsync(colsum, 0, 512 * sizeof(float), stream);
  k_colsum<<<256, 256, 0, stream>>>(fe, colsum);
  k_transpose2<<<dim3(8, 8, 2), 256, 0, stream>>>(wk, wv, wkt, wvt);
  // G = W_ih[:,256:] @ Wo^T   (fp32, 1536x512)
  k_abt<false><<<dim3(8, 24), 256, 0, stream>>>(wih, 768, 256, wo, 512, gmat, 512, 0);
  // Bt[n][k]: rows 0..511 = (W_ctx@Wk)^T, rows 512..1023 = (W_ctx@Wv)^T  (bf16)
  k_abt<true><<<dim3(8, 8), 256, 0, stream>>>(wkt, 512, 0, wctx, 512, btmat, 512, 0);
  k_abt<true><<<dim3(8, 8), 256, 0, stream>>>(wvt, 512, 0, wctx, 512, btmat, 512, 512);
  k_bc<<<4, 256, 0, stream>>>(wk, bk, wv, bv, bctx, bcv);
  k_bias2<<<384, 256, 0, stream>>>(wih, bih, bo, bias2);
  k_h0<<<9, 256, 0, stream>>>(wctx, bctx, colsum, stok, hbuf, pabuf);
  k_q0<<<8, 256, 0, stream>>>(hbuf, wq, bq, qsbuf);
  k_gemm<<<4096, 256, 0, stream>>>(fe, btmat, bcv, ckv);

  for (int s = 0; s < NSTEP; ++s) {
    int cur = s & 1, nxt = cur ^ 1;
    k_attn<<<1024, 256, 0, stream>>>(ckv, qsbuf, pmb, pzb, pctxb);
    k_combine<<<8, 256, 0, stream>>>(pmb, pzb, pctxb, ctxbuf);
    k_matvec<<<768, 256, 0, stream>>>(gmat, wih, whh, bias2, ctxbuf,
                                      pabuf + cur * 256, hbuf + cur * 512, ihpb, hhb);
    k_finish<<<73, 256, 0, stream>>>(ihpb, hhb, bhn, hbuf + cur * 512, wq, bq, wattr, battr,
                                     wconf, bconf, hbuf + nxt * 512, pabuf + nxt * 256,
                                     qsbuf, out + s * 256, out + 4096 + s);
  }
}

// Round 2
// 2554.751 us; speedup vs baseline: 1.0030x; 1.0030x over previous
//
#include <hip/hip_runtime.h>
#include <stdint.h>

#define NF 65536
#define DIM 512
#define NATTR 256
#define NSTEP 16

typedef __attribute__((ext_vector_type(8))) short s16x8;
typedef __attribute__((ext_vector_type(4))) float f32x4;

__device__ __forceinline__ unsigned short f2bf(float f) {
  union { float f; unsigned u; } v; v.f = f;
  return (unsigned short)((v.u + 0x7fffu + ((v.u >> 16) & 1u)) >> 16);
}
__device__ __forceinline__ float bf2f(unsigned short b) {
  union { unsigned u; float f; } v; v.u = ((unsigned)b) << 16;
  return v.f;
}

// ---------------- prep: column sums of fe (for h0 = mean(fe)@W_ctx + b_ctx) ----------------
__global__ void k_colsum(const float* __restrict__ fe, float* __restrict__ colsum) {
  int c = threadIdx.x;                 // 256 threads, 2 cols each
  int r0 = blockIdx.x * 256;           // 256 blocks x 256 rows
  float s0 = 0.f, s1 = 0.f;
  for (int r = r0; r < r0 + 256; ++r) {
    s0 += fe[(size_t)r * DIM + c];
    s1 += fe[(size_t)r * DIM + c + 256];
  }
  atomicAdd(&colsum[c], s0);
  atomicAdd(&colsum[c + 256], s1);
}

// ---------------- prep: transpose Wk, Wv (512x512) ----------------
__global__ void k_transpose2(const float* __restrict__ wk, const float* __restrict__ wv,
                             float* __restrict__ wkt, float* __restrict__ wvt) {
  __shared__ float t[64][65];
  const float* src = blockIdx.z ? wv : wk;
  float* dst = blockIdx.z ? wvt : wkt;
  int c0 = blockIdx.x * 64, r0 = blockIdx.y * 64;
  for (int i = 0; i < 16; ++i) {
    int row = i * 4 + (threadIdx.x >> 6), col = threadIdx.x & 63;
    t[row][col] = src[(r0 + row) * 512 + c0 + col];
  }
  __syncthreads();
  for (int i = 0; i < 16; ++i) {
    int row = i * 4 + (threadIdx.x >> 6), col = threadIdx.x & 63;
    dst[(c0 + row) * 512 + r0 + col] = t[col][row];
  }
}

// ---------------- prep: generic C[M][N] = sum_k A[m][k]*B[n][k]  (K=512) ----------------
template <bool BF16OUT>
__global__ void k_abt(const float* __restrict__ A, int lda, int aoff,
                      const float* __restrict__ B, int ldb,
                      void* __restrict__ C, int ldc, int mbase) {
  __shared__ float ta[64][65], tb[64][65];
  int m0 = blockIdx.y * 64, n0 = blockIdx.x * 64;
  int tid = threadIdx.x;
  float acc[4][4] = {};
  for (int k0 = 0; k0 < 512; k0 += 64) {
    __syncthreads();
    for (int i = 0; i < 16; ++i) {
      int e = i * 256 + tid;
      int row = e >> 6, col = e & 63;
      ta[row][col] = A[(m0 + row) * lda + aoff + k0 + col];
      tb[row][col] = B[(n0 + row) * ldb + k0 + col];
    }
    __syncthreads();
    int tr = (tid >> 4) * 4, tc = (tid & 15) * 4;
#pragma unroll 4
    for (int k = 0; k < 64; ++k) {
      float av[4], bv[4];
#pragma unroll
      for (int i = 0; i < 4; ++i) av[i] = ta[tr + i][k];
#pragma unroll
      for (int j = 0; j < 4; ++j) bv[j] = tb[tc + j][k];
#pragma unroll
      for (int i = 0; i < 4; ++i)
#pragma unroll
        for (int j = 0; j < 4; ++j) acc[i][j] += av[i] * bv[j];
    }
  }
  int tr = (tid >> 4) * 4, tc = (tid & 15) * 4;
  for (int i = 0; i < 4; ++i)
    for (int j = 0; j < 4; ++j) {
      int m = mbase + m0 + tr + i, n = n0 + tc + j;
      if (BF16OUT) ((unsigned short*)C)[(size_t)m * ldc + n] = f2bf(acc[i][j]);
      else ((float*)C)[(size_t)m * ldc + n] = acc[i][j];
    }
}

// ---------------- prep: bc[n] = b_ctx @ Wsel[:,n] + bsel[n] ----------------
__global__ void k_bc(const float* __restrict__ wk, const float* __restrict__ bk,
                     const float* __restrict__ wv, const float* __restrict__ bv,
                     const float* __restrict__ bctx, float* __restrict__ bc) {
  int n = blockIdx.x * 256 + threadIdx.x;
  const float* w = n < 512 ? wk : wv;
  const float* b = n < 512 ? bk : bv;
  int col = n & 511;
  float s = b[col];
  for (int t = 0; t < 512; ++t) s += bctx[t] * w[t * 512 + col];
  bc[n] = s;
}

// ---------------- prep: bias2[r] = b_ih[r] + W_ih[r,256:] @ bo ----------------
__global__ void k_bias2(const float* __restrict__ wih, const float* __restrict__ bih,
                        const float* __restrict__ bo, float* __restrict__ bias2) {
  int r = blockIdx.x * 4 + (threadIdx.x >> 6);
  int l = threadIdx.x & 63;
  float s = 0.f;
  for (int j = l; j < 512; j += 64) s += wih[r * 768 + 256 + j] * bo[j];
  for (int mk = 1; mk < 64; mk <<= 1) s += __shfl_xor(s, mk);
  if (l == 0) bias2[r] = s + bih[r];
}

// ---------------- prep: h0 + copy start token ----------------
__global__ void k_h0(const float* __restrict__ wctx, const float* __restrict__ bctx,
                     const float* __restrict__ colsum, const float* __restrict__ stok,
                     float* __restrict__ h, float* __restrict__ pa) {
  if (blockIdx.x == 8) {
    if (threadIdx.x < 256) pa[threadIdx.x] = stok[threadIdx.x];
    return;
  }
  __shared__ float red[4][64];
  int c = blockIdx.x * 64 + (threadIdx.x & 63);
  int chunk = threadIdx.x >> 6;
  float s = 0.f;
  for (int i = chunk * 128; i < chunk * 128 + 128; ++i) s += colsum[i] * wctx[i * 512 + c];
  red[chunk][threadIdx.x & 63] = s;
  __syncthreads();
  if (threadIdx.x < 64) {
    int cc = blockIdx.x * 64 + threadIdx.x;
    float v = red[0][threadIdx.x] + red[1][threadIdx.x] + red[2][threadIdx.x] + red[3][threadIdx.x];
    h[cc] = v * (1.0f / NF) + bctx[cc];
  }
}

// ---------------- prep: qs = (h @ Wq + bq) / 8 ----------------
__global__ void k_q0(const float* __restrict__ h, const float* __restrict__ wq,
                     const float* __restrict__ bq, float* __restrict__ qs) {
  __shared__ float red[4][64];
  int j = blockIdx.x * 64 + (threadIdx.x & 63);
  int chunk = threadIdx.x >> 6;
  float s = 0.f;
  for (int i = chunk * 128; i < chunk * 128 + 128; ++i) s += h[i] * wq[i * 512 + j];
  red[chunk][threadIdx.x & 63] = s;
  __syncthreads();
  if (threadIdx.x < 64) {
    int jj = blockIdx.x * 64 + threadIdx.x;
    float v = red[0][threadIdx.x] + red[1][threadIdx.x] + red[2][threadIdx.x] + red[3][threadIdx.x];
    qs[jj] = (v + bq[jj]) * 0.125f;
  }
}

// ---------------- big dual GEMM: C_kv[65536][1024](bf16) = fe @ Bt^T + bc ----------------
// XCD-locality fix: m-tile index in the LOW bits so the 8 n-tiles sharing an
// A-panel differ by 512 (multiple of 8) in block index -> same XCD L2.
__global__ __launch_bounds__(256) void k_gemm(const float* __restrict__ fe,
                                              const unsigned short* __restrict__ bt,
                                              const float* __restrict__ bc,
                                              unsigned short* __restrict__ ckv) {
  __shared__ unsigned short lA[128 * 64];
  __shared__ unsigned short lB[128 * 64];
  int bx = blockIdx.x;
  int m0 = (bx & 511) * 128, n0 = (bx >> 9) * 128;
  int t = threadIdx.x, l = t & 63, w = t >> 6;
  int wr = (w >> 1) * 64, wc = (w & 1) * 64;
  int lm = l & 15, lkb = (l >> 4) * 16;
  int swz = (lm & 7) << 4;
  f32x4 acc[4][4] = {};
  for (int k0 = 0; k0 < 512; k0 += 64) {
    __syncthreads();
#pragma unroll
    for (int i = 0; i < 8; ++i) {  // stage A: 128x64 fp32 -> bf16
      int e = i * 1024 + t * 4;
      int row = e >> 6, col = e & 63;
      float4 v = *(const float4*)&fe[(size_t)(m0 + row) * 512 + k0 + col];
      unsigned long long pk;
      unsigned short* pu = (unsigned short*)&pk;
      pu[0] = f2bf(v.x); pu[1] = f2bf(v.y); pu[2] = f2bf(v.z); pu[3] = f2bf(v.w);
      *(unsigned long long*)((char*)lA + row * 128 + ((col * 2) ^ ((row & 7) << 4))) = pk;
    }
#pragma unroll
    for (int i = 0; i < 4; ++i) {  // stage B: 128x64 bf16
      int e = i * 2048 + t * 8;
      int row = e >> 6, col = e & 63;
      uint4 v = *(const uint4*)&bt[(size_t)(n0 + row) * 512 + k0 + col];
      *(uint4*)((char*)lB + row * 128 + ((col * 2) ^ ((row & 7) << 4))) = v;
    }
    __syncthreads();
#pragma unroll
    for (int ks = 0; ks < 2; ++ks) {
      s16x8 af[4], bf_[4];
      int kb = ks * 64 + lkb;
#pragma unroll
      for (int mi = 0; mi < 4; ++mi)
        af[mi] = *(const s16x8*)((const char*)lA + (wr + mi * 16 + lm) * 128 + (kb ^ swz));
#pragma unroll
      for (int ni = 0; ni < 4; ++ni)
        bf_[ni] = *(const s16x8*)((const char*)lB + (wc + ni * 16 + lm) * 128 + (kb ^ swz));
#pragma unroll
      for (int mi = 0; mi < 4; ++mi)
#pragma unroll
        for (int ni = 0; ni < 4; ++ni)
          acc[mi][ni] = __builtin_amdgcn_mfma_f32_16x16x32_bf16(af[mi], bf_[ni], acc[mi][ni], 0, 0, 0);
    }
  }
#pragma unroll
  for (int mi = 0; mi < 4; ++mi)
#pragma unroll
    for (int ni = 0; ni < 4; ++ni) {
      int n = n0 + wc + ni * 16 + lm;
      float bias = bc[n];
#pragma unroll
      for (int r = 0; r < 4; ++r) {
        int m = m0 + wr + mi * 16 + (l >> 4) * 4 + r;
        ckv[(size_t)m * 1024 + n] = f2bf(acc[mi][ni][r] + bias);
      }
    }
}

// ---------------- step: streaming attention, chunked branchless online softmax ----------------
// ckv rows: [k(512 bf16) | v(512 bf16)]. Lane l owns cols l*8..l*8+7 (head l>>3).
__global__ __launch_bounds__(256) void k_attn(const unsigned short* __restrict__ ckv,
                                              const float* __restrict__ qs,
                                              float* __restrict__ pm, float* __restrict__ pz,
                                              float* __restrict__ pctx) {
  int t = threadIdx.x, l = t & 63, w = t >> 6;
  int h = l >> 3;
  float qr[8];
  {
    float4 q0 = *(const float4*)&qs[l * 8];
    float4 q1 = *(const float4*)&qs[l * 8 + 4];
    qr[0] = q0.x; qr[1] = q0.y; qr[2] = q0.z; qr[3] = q0.w;
    qr[4] = q1.x; qr[5] = q1.y; qr[6] = q1.z; qr[7] = q1.w;
  }
  float m = -1e30f, Z = 0.f, acc[8] = {};
  int r0 = blockIdx.x * 64 + w * 16;
#pragma unroll
  for (int c = 0; c < 2; ++c) {
    int rb = r0 + c * 8;
    uint4 kk[8], vv[8];
#pragma unroll
    for (int j = 0; j < 8; ++j) {  // all 16 loads issued up front
      const uint4* row = (const uint4*)(ckv + (size_t)(rb + j) * 1024);
      kk[j] = row[l];
      vv[j] = row[64 + l];
    }
    float dot[8];
#pragma unroll
    for (int j = 0; j < 8; ++j) {
      unsigned ku[4] = {kk[j].x, kk[j].y, kk[j].z, kk[j].w};
      float d = 0.f;
#pragma unroll
      for (int q2 = 0; q2 < 4; ++q2) {
        d += bf2f((unsigned short)(ku[q2] & 0xffffu)) * qr[2 * q2];
        d += bf2f((unsigned short)(ku[q2] >> 16)) * qr[2 * q2 + 1];
      }
      d += __shfl_xor(d, 1);
      d += __shfl_xor(d, 2);
      d += __shfl_xor(d, 4);
      dot[j] = d;
    }
    float cm = fmaxf(fmaxf(fmaxf(dot[0], dot[1]), fmaxf(dot[2], dot[3])),
                     fmaxf(fmaxf(dot[4], dot[5]), fmaxf(dot[6], dot[7])));
    float nm = fmaxf(m, cm);
    float f = __expf(m - nm);
    m = nm;
    Z *= f;
#pragma unroll
    for (int d2 = 0; d2 < 8; ++d2) acc[d2] *= f;
    float wgt[8];
#pragma unroll
    for (int j = 0; j < 8; ++j) { wgt[j] = __expf(dot[j] - m); Z += wgt[j]; }
#pragma unroll
    for (int j = 0; j < 8; ++j) {
      unsigned vu[4] = {vv[j].x, vv[j].y, vv[j].z, vv[j].w};
#pragma unroll
      for (int q2 = 0; q2 < 4; ++q2) {
        acc[2 * q2]     += wgt[j] * bf2f((unsigned short)(vu[q2] & 0xffffu));
        acc[2 * q2 + 1] += wgt[j] * bf2f((unsigned short)(vu[q2] >> 16));
      }
    }
  }
  __shared__ float sm[4][8], sz[4][8], sc[4][8][64];
  if ((l & 7) == 0) { sm[w][h] = m; sz[w][h] = Z; }
#pragma unroll
  for (int j = 0; j < 8; ++j) sc[w][h][(l & 7) * 8 + j] = acc[j];
  __syncthreads();
  for (int i = t; i < 512; i += 256) {
    int hh = i >> 6, d = i & 63;
    float M = fmaxf(fmaxf(sm[0][hh], sm[1][hh]), fmaxf(sm[2][hh], sm[3][hh]));
    float c = 0.f;
    for (int ww = 0; ww < 4; ++ww) c += sc[ww][hh][d] * __expf(sm[ww][hh] - M);
    pctx[((size_t)blockIdx.x * 8 + hh) * 64 + d] = c;
    if (d == 0) {
      float zz = 0.f;
      for (int ww = 0; ww < 4; ++ww) zz += sz[ww][hh] * __expf(sm[ww][hh] - M);
      pm[blockIdx.x * 8 + hh] = M;
      pz[blockIdx.x * 8 + hh] = zz;
    }
  }
}

// ---------------- step: combine block partials -> normalized ctx[512] ----------------
__global__ void k_combine(const float* __restrict__ pm, const float* __restrict__ pz,
                          const float* __restrict__ pctx, float* __restrict__ ctx) {
  int h = blockIdx.x, t = threadIdx.x;
  __shared__ float smax[256];
  float lm = -1e30f;
  for (int b = t; b < 1024; b += 256) lm = fmaxf(lm, pm[b * 8 + h]);
  smax[t] = lm;
  __syncthreads();
  for (int s = 128; s > 0; s >>= 1) {
    if (t < s) smax[t] = fmaxf(smax[t], smax[t + s]);
    __syncthreads();
  }
  float M = smax[0];
  int d = t & 63, g = t >> 6;
  float ca = 0.f, za = 0.f;
  for (int b = g; b < 1024; b += 4) {
    float f = __expf(pm[b * 8 + h] - M);
    ca += pctx[((size_t)b * 8 + h) * 64 + d] * f;
    if (d == 0) za += pz[b * 8 + h] * f;
  }
  __shared__ float cs[4][64], zs[4];
  cs[g][d] = ca;
  if (d == 0) zs[g] = za;
  __syncthreads();
  if (t < 64) {
    float c = cs[0][t] + cs[1][t] + cs[2][t] + cs[3][t];
    float Zt = zs[0] + zs[1] + zs[2] + zs[3];
    ctx[h * 64 + t] = c / Zt;
  }
}

// ---------------- step: ih_pre = G@ctx + W_ih[:, :256]@pa + bias2 ; hh = W_hh@h ----------------
__global__ void k_matvec(const float* __restrict__ G, const float* __restrict__ wih,
                         const float* __restrict__ whh, const float* __restrict__ bias2,
                         const float* __restrict__ ctx, const float* __restrict__ pa,
                         const float* __restrict__ h, float* __restrict__ ihp,
                         float* __restrict__ hh) {
  int r = blockIdx.x * 4 + (threadIdx.x >> 6);
  int l = threadIdx.x & 63;
  float s = 0.f;
  if (r < 1536) {
    for (int i = l; i < 512; i += 64) s += G[r * 512 + i] * ctx[i];
    for (int i = l; i < 256; i += 64) s += wih[r * 768 + i] * pa[i];
  } else {
    int r2 = r - 1536;
    for (int i = l; i < 512; i += 64) s += whh[r2 * 512 + i] * h[i];
  }
  for (int mk = 1; mk < 64; mk <<= 1) s += __shfl_xor(s, mk);
  if (l == 0) {
    if (r < 1536) ihp[r] = s + bias2[r];
    else hh[r - 1536] = s;
  }
}

// ---------------- step: GRU gates + heads + next q ----------------
__global__ void k_finish(const float* __restrict__ ihp, const float* __restrict__ hhv,
                         const float* __restrict__ bhn, const float* __restrict__ hold,
                         const float* __restrict__ wq, const float* __restrict__ bq,
                         const float* __restrict__ wattr, const float* __restrict__ battr,
                         const float* __restrict__ wconf, const float* __restrict__ bconf,
                         float* __restrict__ hnew_g, float* __restrict__ panew,
                         float* __restrict__ qs, float* __restrict__ out_a,
                         float* __restrict__ out_c) {
  __shared__ float hn[512];
  __shared__ float red[4][64];
  int t = threadIdx.x;
  for (int c = t; c < 512; c += 256) {
    float ir = ihp[c], iz = ihp[512 + c], inn = ihp[1024 + c];
    float hr = hhv[c], hz = hhv[512 + c], hnn = hhv[1024 + c];
    float r = 1.f / (1.f + __expf(-(ir + hr)));
    float z = 1.f / (1.f + __expf(-(iz + hz)));
    float n = tanhf(inn + r * (hnn + bhn[c]));
    hn[c] = (1.f - z) * n + z * hold[c];
  }
  __syncthreads();
  int b = blockIdx.x;
  if (b < 8) {
    int j = b * 64 + (t & 63), chunk = t >> 6;
    float s = 0.f;
    for (int i = chunk * 128; i < chunk * 128 + 128; ++i) s += hn[i] * wq[i * 512 + j];
    red[chunk][t & 63] = s;
    __syncthreads();
    if (t < 64) {
      int jj = b * 64 + t;
      qs[jj] = (red[0][t] + red[1][t] + red[2][t] + red[3][t] + bq[jj]) * 0.125f;
    }
  } else if (b < 72) {
    int r = (b - 8) * 4 + (t >> 6), l = t & 63;
    float s = 0.f;
    for (int i = l; i < 512; i += 64) s += wattr[r * 512 + i] * hn[i];
    for (int mk = 1; mk < 64; mk <<= 1) s += __shfl_xor(s, mk);
    if (l == 0) {
      float a = s + battr[r];
      out_a[r] = a;
      panew[r] = a;
    }
  } else {
    if (t < 64) {
      float s = 0.f;
      for (int i = t; i < 512; i += 64) s += wconf[i] * hn[i];
      for (int mk = 1; mk < 64; mk <<= 1) s += __shfl_xor(s, mk);
      if (t == 0) out_c[0] = 1.f / (1.f + __expf(-(s + bconf[0])));
    }
    for (int c = t; c < 512; c += 256) hnew_g[c] = hn[c];
  }
}

extern "C" void kernel_launch(void* const* d_in, const int* in_sizes, int n_in,
                              void* d_out, int out_size, void* d_ws, size_t ws_size,
                              hipStream_t stream) {
  (void)in_sizes; (void)n_in; (void)out_size; (void)ws_size;
  const float* fe    = (const float*)d_in[0];
  const float* wctx  = (const float*)d_in[1];
  const float* bctx  = (const float*)d_in[2];
  const float* wq    = (const float*)d_in[3];
  const float* bq    = (const float*)d_in[4];
  const float* wk    = (const float*)d_in[5];
  const float* bk    = (const float*)d_in[6];
  const float* wv    = (const float*)d_in[7];
  const float* bv    = (const float*)d_in[8];
  const float* wo    = (const float*)d_in[9];
  const float* bo    = (const float*)d_in[10];
  const float* wih   = (const float*)d_in[11];
  const float* whh   = (const float*)d_in[12];
  const float* bih   = (const float*)d_in[13];
  const float* bhn   = (const float*)d_in[14];
  const float* stok  = (const float*)d_in[15];
  const float* wattr = (const float*)d_in[16];
  const float* battr = (const float*)d_in[17];
  const float* wconf = (const float*)d_in[18];
  const float* bconf = (const float*)d_in[19];
  float* out = (float*)d_out;

  char* ws = (char*)d_ws;
  unsigned short* ckv   = (unsigned short*)(ws + 0);            // 134217728 B
  unsigned short* btmat = (unsigned short*)(ws + 134217728);    // 1048576 B
  float* wkt    = (float*)(ws + 135266304);
  float* wvt    = (float*)(ws + 136314880);
  float* gmat   = (float*)(ws + 137363456);
  float* bcv    = (float*)(ws + 140509184);
  float* bias2  = (float*)(ws + 140513280);
  float* colsum = (float*)(ws + 140519424);
  float* hbuf   = (float*)(ws + 140521472);
  float* pabuf  = (float*)(ws + 140525568);
  float* qsbuf  = (float*)(ws + 140527616);
  float* ctxbuf = (float*)(ws + 140529664);
  float* ihpb   = (float*)(ws + 140531712);
  float* hhb    = (float*)(ws + 140537856);
  float* pmb    = (float*)(ws + 140544000);
  float* pzb    = (float*)(ws + 140576768);
  float* pctxb  = (float*)(ws + 140609536);

  hipMemsetAsync(colsum, 0, 512 * sizeof(float), stream);
  k_colsum<<<256, 256, 0, stream>>>(fe, colsum);
  k_transpose2<<<dim3(8, 8, 2), 256, 0, stream>>>(wk, wv, wkt, wvt);
  k_abt<false><<<dim3(8, 24), 256, 0, stream>>>(wih, 768, 256, wo, 512, gmat, 512, 0);
  k_abt<true><<<dim3(8, 8), 256, 0, stream>>>(wkt, 512, 0, wctx, 512, btmat, 512, 0);
  k_abt<true><<<dim3(8, 8), 256, 0, stream>>>(wvt, 512, 0, wctx, 512, btmat, 512, 512);
  k_bc<<<4, 256, 0, stream>>>(wk, bk, wv, bv, bctx, bcv);
  k_bias2<<<384, 256, 0, stream>>>(wih, bih, bo, bias2);
  k_h0<<<9, 256, 0, stream>>>(wctx, bctx, colsum, stok, hbuf, pabuf);
  k_q0<<<8, 256, 0, stream>>>(hbuf, wq, bq, qsbuf);
  k_gemm<<<4096, 256, 0, stream>>>(fe, btmat, bcv, ckv);

  for (int s = 0; s < NSTEP; ++s) {
    int cur = s & 1, nxt = cur ^ 1;
    k_attn<<<1024, 256, 0, stream>>>(ckv, qsbuf, pmb, pzb, pctxb);
    k_combine<<<8, 256, 0, stream>>>(pmb, pzb, pctxb, ctxbuf);
    k_matvec<<<768, 256, 0, stream>>>(gmat, wih, whh, bias2, ctxbuf,
                                      pabuf + cur * 256, hbuf + cur * 512, ihpb, hhb);
    k_finish<<<73, 256, 0, stream>>>(ihpb, hhb, bhn, hbuf + cur * 512, wq, bq, wattr, battr,
                                     wconf, bconf, hbuf + nxt * 512, pabuf + nxt * 256,
                                     qsbuf, out + s * 256, out + 4096 + s);
  }
}